// Round 5
// baseline (342.311 us; speedup 1.0000x reference)
//
#include <hip/hip_runtime.h>
#include <hip/hip_bf16.h>
#include <math.h>

// Problem dims (fixed)
#define BB 2
#define SS 512
#define DD 256
#define FFD 1024
#define HH 4
#define NN 512
#define PP 32
#define KK 16
#define KPP 4
#define RR 64
#define DHH 64
#define TT (BB*SS)   // 1024 tokens
#define QT 16        // attn queries per block

// ---------------------------------------------------------------------------
__global__ __launch_bounds__(64) void zero_kernel(int* __restrict__ p, int n)
{
    int i = threadIdx.x;
    if (i < n) p[i] = 0;
}

// ---------------------------------------------------------------------------
// LayerNorm: produces n1 = LN(x,g1,b1), n2 = LN(x,g2,b2). One block per token.
// ---------------------------------------------------------------------------
__global__ __launch_bounds__(256) void ln_kernel(
    const float* __restrict__ x,
    const float* __restrict__ g1, const float* __restrict__ b1,
    const float* __restrict__ g2, const float* __restrict__ b2,
    float* __restrict__ n1, float* __restrict__ n2)
{
    int t = blockIdx.x;
    int d = threadIdx.x;
    __shared__ float red[256];
    float v = x[t*DD + d];
    red[d] = v; __syncthreads();
    for (int s = 128; s > 0; s >>= 1) { if (d < s) red[d] += red[d+s]; __syncthreads(); }
    float mu = red[0] * (1.0f/DD);
    __syncthreads();
    float dv = v - mu;
    red[d] = dv*dv; __syncthreads();
    for (int s = 128; s > 0; s >>= 1) { if (d < s) red[d] += red[d+s]; __syncthreads(); }
    float var = red[0] * (1.0f/DD);
    float r = 1.0f / sqrtf(var + 1e-5f);
    n1[t*DD+d] = dv*r*g1[d] + b1[d];
    n2[t*DD+d] = dv*r*g2[d] + b2[d];
}

// ---------------------------------------------------------------------------
// GEMM body v2: 64x64 tile, BK=32, 256 threads, register double-buffering.
//   mode 0: none; 1: sigmoid; 2: gelu(0.1*val+0.9*sum4slices(extra)); 3: val+extra
// ---------------------------------------------------------------------------
__device__ __forceinline__ void gemm_body(
    const float* __restrict__ A, const float* __restrict__ Bm,
    const float* __restrict__ bias, const float* __restrict__ extra,
    float* __restrict__ C, int M, int Nn, int Kk, int transB, int mode,
    int k0off, int kLen)
{
    __shared__ float As[2][32][68];   // As[buf][k][m] (transposed)
    __shared__ float Bs[2][32][68];   // Bs[buf][k][n]
    int bm = blockIdx.y * 64;
    int bn = blockIdx.x * 64;
    int tid = threadIdx.x;
    int tx = tid & 15, ty = tid >> 4;

    float4 pa[2], pb[2];

    #define LOAD_A(kbase) { \
        _Pragma("unroll") \
        for (int e = 0; e < 2; ++e) { \
            int r = e*32 + (tid>>3); int c4 = tid & 7; \
            pa[e] = *(const float4*)&A[(size_t)(bm + r)*Kk + (kbase) + c4*4]; \
        } }
    #define STORE_A(buf) { \
        _Pragma("unroll") \
        for (int e = 0; e < 2; ++e) { \
            int r = e*32 + (tid>>3); int c4 = tid & 7; \
            As[buf][c4*4+0][r] = pa[e].x; \
            As[buf][c4*4+1][r] = pa[e].y; \
            As[buf][c4*4+2][r] = pa[e].z; \
            As[buf][c4*4+3][r] = pa[e].w; \
        } }
    #define LOAD_B(kbase) { \
        if (transB == 0) { \
            _Pragma("unroll") \
            for (int e = 0; e < 2; ++e) { \
                int c = e*16 + (tid>>4); int n4 = tid & 15; \
                pb[e] = *(const float4*)&Bm[(size_t)((kbase) + c)*Nn + bn + n4*4]; \
            } \
        } else { \
            _Pragma("unroll") \
            for (int e = 0; e < 2; ++e) { \
                int r = e*32 + (tid>>3); int k4 = tid & 7; \
                pb[e] = *(const float4*)&Bm[(size_t)(bn + r)*Kk + (kbase) + k4*4]; \
            } \
        } }
    #define STORE_B(buf) { \
        if (transB == 0) { \
            _Pragma("unroll") \
            for (int e = 0; e < 2; ++e) { \
                int c = e*16 + (tid>>4); int n4 = tid & 15; \
                *(float4*)&Bs[buf][c][n4*4] = pb[e]; \
            } \
        } else { \
            _Pragma("unroll") \
            for (int e = 0; e < 2; ++e) { \
                int r = e*32 + (tid>>3); int k4 = tid & 7; \
                Bs[buf][k4*4+0][r] = pb[e].x; \
                Bs[buf][k4*4+1][r] = pb[e].y; \
                Bs[buf][k4*4+2][r] = pb[e].z; \
                Bs[buf][k4*4+3][r] = pb[e].w; \
            } \
        } }

    float acc[4][4] = {};
    int nk = kLen >> 5;   // BK=32

    LOAD_A(k0off); LOAD_B(k0off);
    STORE_A(0); STORE_B(0);
    __syncthreads();

    for (int kt = 0; kt < nk; ++kt) {
        int cur = kt & 1;
        if (kt + 1 < nk) { LOAD_A(k0off + (kt+1)*32); LOAD_B(k0off + (kt+1)*32); }
        #pragma unroll
        for (int kk = 0; kk < 32; ++kk) {
            float4 av = *(const float4*)&As[cur][kk][ty*4];
            float4 bv = *(const float4*)&Bs[cur][kk][tx*4];
            acc[0][0] = fmaf(av.x, bv.x, acc[0][0]);
            acc[0][1] = fmaf(av.x, bv.y, acc[0][1]);
            acc[0][2] = fmaf(av.x, bv.z, acc[0][2]);
            acc[0][3] = fmaf(av.x, bv.w, acc[0][3]);
            acc[1][0] = fmaf(av.y, bv.x, acc[1][0]);
            acc[1][1] = fmaf(av.y, bv.y, acc[1][1]);
            acc[1][2] = fmaf(av.y, bv.z, acc[1][2]);
            acc[1][3] = fmaf(av.y, bv.w, acc[1][3]);
            acc[2][0] = fmaf(av.z, bv.x, acc[2][0]);
            acc[2][1] = fmaf(av.z, bv.y, acc[2][1]);
            acc[2][2] = fmaf(av.z, bv.z, acc[2][2]);
            acc[2][3] = fmaf(av.z, bv.w, acc[2][3]);
            acc[3][0] = fmaf(av.w, bv.x, acc[3][0]);
            acc[3][1] = fmaf(av.w, bv.y, acc[3][1]);
            acc[3][2] = fmaf(av.w, bv.z, acc[3][2]);
            acc[3][3] = fmaf(av.w, bv.w, acc[3][3]);
        }
        if (kt + 1 < nk) {
            STORE_A(cur^1); STORE_B(cur^1);
            __syncthreads();
        }
    }

    #pragma unroll
    for (int i = 0; i < 4; ++i) {
        int m = bm + ty*4 + i;
        #pragma unroll
        for (int j = 0; j < 4; ++j) {
            int n = bn + tx*4 + j;
            float val = acc[i][j] + (bias ? bias[n] : 0.0f);
            if (mode == 1) {
                val = 1.0f / (1.0f + expf(-val));
            } else if (mode == 2) {
                size_t idx = (size_t)m*Nn + n;
                float hp = extra[idx] + extra[idx + (size_t)TT*FFD]
                         + extra[idx + 2*(size_t)TT*FFD] + extra[idx + 3*(size_t)TT*FFD];
                float z = 0.1f*val + 0.9f*hp;
                val = 0.5f*z*(1.0f + erff(z*0.70710678118654752f));
            } else if (mode == 3) {
                val = val + extra[(size_t)m*Nn+n];
            }
            C[(size_t)m*Nn + n] = val;
        }
    }
    #undef LOAD_A
    #undef STORE_A
    #undef LOAD_B
    #undef STORE_B
}

__global__ __launch_bounds__(256) void gemm_kernel(
    const float* __restrict__ A, const float* __restrict__ Bm,
    const float* __restrict__ bias, const float* __restrict__ extra,
    float* __restrict__ C, int M, int Nn, int Kk, int transB, int mode)
{
    gemm_body(A, Bm, bias, extra, C, M, Nn, Kk, transB, mode, 0, Kk);
}

struct GemmSet { const float* A; const float* B; const float* bias; float* C; int mode; };

__global__ __launch_bounds__(256) void gemm3_kernel(
    GemmSet s0, GemmSet s1, GemmSet s2, int M, int Nn, int Kk, int transB)
{
    GemmSet s = (blockIdx.z == 0) ? s0 : ((blockIdx.z == 1) ? s1 : s2);
    gemm_body(s.A, s.B, s.bias, nullptr, s.C, M, Nn, Kk, transB, s.mode, 0, Kk);
}

__global__ __launch_bounds__(256) void gemm_splitk_kernel(
    const float* __restrict__ A, const float* __restrict__ Bm,
    float* __restrict__ Cpart, int M, int Nn, int Kk, int kPerSplit)
{
    int sk = blockIdx.z;
    float* Cp = Cpart + (size_t)sk * M * Nn;
    gemm_body(A, Bm, nullptr, nullptr, Cp, M, Nn, Kk, 0, 0, sk*kPerSplit, kPerSplit);
}

__global__ __launch_bounds__(256) void combine_wd_kernel(
    const float* __restrict__ part, const float* __restrict__ x,
    const float* __restrict__ bd, float* __restrict__ out)
{
    int i = blockIdx.x*256 + threadIdx.x;
    int d = i & (DD-1);
    float s = x[i] + bd[d];
    s += part[i] + part[i + TT*DD] + part[i + 2*TT*DD] + part[i + 3*TT*DD];
    out[i] = s;
}

// ---------------------------------------------------------------------------
// Flash-style attention: block = (b, h, 16-query tile). 256 blocks, 256 thr.
// ---------------------------------------------------------------------------
__global__ __launch_bounds__(256) void attn_kernel(
    const float* __restrict__ q, const float* __restrict__ k,
    const float* __restrict__ v, float* __restrict__ ctx)
{
    int bi = blockIdx.x;
    int qt = bi & 31;
    int bh = bi >> 5;
    int h = bh & (HH-1);
    int b = bh >> 2;
    int tid = threadIdx.x;
    int qo = tid >> 4;
    int c  = tid & 15;

    __shared__ float Qs[QT][68];
    __shared__ float Kt[64][64];
    __shared__ float Vs[64][68];
    __shared__ float Ps[QT][68];

    {
        const float* qp = q + ((size_t)(b*SS + qt*QT + qo)*DD) + h*DHH + c*4;
        *(float4*)&Qs[qo][c*4] = *(const float4*)qp;
    }
    float O0=0.f, O1=0.f, O2=0.f, O3=0.f;
    float mreg = -3.4e38f, lreg = 0.f;

    for (int t = 0; t < 8; ++t) {
        if (t) __syncthreads();
        #pragma unroll
        for (int e = 0; e < 4; ++e) {
            int lin = e*256 + tid;
            int kr = lin & 63;
            int c4 = lin >> 6;
            const float* kp = k + ((size_t)(b*SS + t*64 + kr)*DD) + h*DHH + c4*4;
            float4 kv = *(const float4*)kp;
            Kt[c4*4+0][kr] = kv.x;
            Kt[c4*4+1][kr] = kv.y;
            Kt[c4*4+2][kr] = kv.z;
            Kt[c4*4+3][kr] = kv.w;
            int vr = lin >> 4;
            int vc = lin & 15;
            const float* vp = v + ((size_t)(b*SS + t*64 + vr)*DD) + h*DHH + vc*4;
            *(float4*)&Vs[vr][vc*4] = *(const float4*)vp;
        }
        __syncthreads();
        float s0=0.f, s1=0.f, s2=0.f, s3=0.f;
        #pragma unroll 8
        for (int d = 0; d < 64; ++d) {
            float qv = Qs[qo][d];
            float4 kv = *(const float4*)&Kt[d][c*4];
            s0 = fmaf(qv, kv.x, s0);
            s1 = fmaf(qv, kv.y, s1);
            s2 = fmaf(qv, kv.z, s2);
            s3 = fmaf(qv, kv.w, s3);
        }
        s0 *= 0.125f; s1 *= 0.125f; s2 *= 0.125f; s3 *= 0.125f;
        float mx = fmaxf(fmaxf(s0, s1), fmaxf(s2, s3));
        #pragma unroll
        for (int mk = 1; mk <= 8; mk <<= 1)
            mx = fmaxf(mx, __shfl_xor(mx, mk));
        float mnew = fmaxf(mreg, mx);
        float scl = __expf(mreg - mnew);
        float e0 = __expf(s0 - mnew), e1 = __expf(s1 - mnew),
              e2 = __expf(s2 - mnew), e3 = __expf(s3 - mnew);
        float esum = e0 + e1 + e2 + e3;
        #pragma unroll
        for (int mk = 1; mk <= 8; mk <<= 1)
            esum += __shfl_xor(esum, mk);
        lreg = lreg * scl + esum;
        mreg = mnew;
        float4 pw; pw.x = e0; pw.y = e1; pw.z = e2; pw.w = e3;
        *(float4*)&Ps[qo][c*4] = pw;
        __syncthreads();
        O0 *= scl; O1 *= scl; O2 *= scl; O3 *= scl;
        #pragma unroll 8
        for (int kk = 0; kk < 64; ++kk) {
            float pv = Ps[qo][kk];
            float4 vv = *(const float4*)&Vs[kk][c*4];
            O0 = fmaf(pv, vv.x, O0);
            O1 = fmaf(pv, vv.y, O1);
            O2 = fmaf(pv, vv.z, O2);
            O3 = fmaf(pv, vv.w, O3);
        }
    }
    float linv = 1.0f / lreg;
    float4 o4; o4.x = O0*linv; o4.y = O1*linv; o4.z = O2*linv; o4.w = O3*linv;
    *(float4*)(ctx + ((size_t)(b*SS + qt*QT + qo)*DD) + h*DHH + c*4) = o4;
}

// ---------------------------------------------------------------------------
// Path softmax + score mix + stable top-16 (shfl-based). Block per token.
// ---------------------------------------------------------------------------
__global__ __launch_bounds__(256) void route_kernel(
    const float* __restrict__ n1, const float* __restrict__ ctx,
    const float* __restrict__ Wpath, const float* __restrict__ bpath,
    const float* __restrict__ ts, const float* __restrict__ cs,
    int* __restrict__ topk_idx, float* __restrict__ topk_w,
    float* __restrict__ out_idx)
{
    int t = blockIdx.x, tid = threadIdx.x;
    int wv = tid >> 6;
    __shared__ float pw0[4], pw1[4];
    float a = n1[t*DD+tid], c = ctx[t*DD+tid];
    float r0 = a * Wpath[tid*2+0] + c * Wpath[(DD+tid)*2+0];
    float r1 = a * Wpath[tid*2+1] + c * Wpath[(DD+tid)*2+1];
    #pragma unroll
    for (int off = 1; off < 64; off <<= 1) {
        r0 += __shfl_xor(r0, off);
        r1 += __shfl_xor(r1, off);
    }
    if ((tid & 63) == 0) { pw0[wv] = r0; pw1[wv] = r1; }
    __syncthreads();
    __shared__ float w0s, w1s;
    if (tid == 0) {
        float l0 = pw0[0]+pw0[1]+pw0[2]+pw0[3] + bpath[0];
        float l1 = pw1[0]+pw1[1]+pw1[2]+pw1[3] + bpath[1];
        float mm = fmaxf(l0, l1);
        float e0 = expf(l0-mm), e1 = expf(l1-mm);
        float is = 1.0f/(e0+e1);
        w0s = e0*is; w1s = e1*is;
    }
    __syncthreads();
    float w0 = w0s, w1 = w1s;
    __shared__ float sc[NN];
    sc[tid]     = w0*ts[t*NN+tid]     + w1*cs[t*NN+tid];
    sc[tid+256] = w0*ts[t*NN+tid+256] + w1*cs[t*NN+tid+256];
    __syncthreads();
    __shared__ float wvv[4]; __shared__ int wvi[4];
    __shared__ float selv[KK]; __shared__ int seli[KK];
    for (int it = 0; it < KK; ++it) {
        float v0 = sc[tid], v1 = sc[tid+256];
        float bv; int bi;
        if (v0 >= v1) { bv = v0; bi = tid; } else { bv = v1; bi = tid+256; }
        #pragma unroll
        for (int off = 1; off < 64; off <<= 1) {
            float ov = __shfl_xor(bv, off);
            int   oi = __shfl_xor(bi, off);
            if (ov > bv || (ov == bv && oi < bi)) { bv = ov; bi = oi; }
        }
        if ((tid & 63) == 0) { wvv[wv] = bv; wvi[wv] = bi; }
        __syncthreads();
        if (tid == 0) {
            float fv = wvv[0]; int fi = wvi[0];
            #pragma unroll
            for (int w = 1; w < 4; ++w) {
                float ov = wvv[w]; int oi = wvi[w];
                if (ov > fv || (ov == fv && oi < fi)) { fv = ov; fi = oi; }
            }
            selv[it] = fv; seli[it] = fi; sc[fi] = -3.4e38f;
        }
        __syncthreads();
    }
    if (tid == 0) {
        float mx = selv[0];
        float e[KK]; float sum = 0.f;
        for (int i = 0; i < KK; ++i) { e[i] = expf(selv[i]-mx); sum += e[i]; }
        float is = 1.0f/sum;
        for (int i = 0; i < KK; ++i) {
            topk_idx[t*KK+i] = seli[i];
            topk_w[t*KK+i]   = e[i]*is;
            out_idx[t*KK+i]  = (float)seli[i];
        }
    }
}

// ---------------------------------------------------------------------------
// InteractionFFN: block per token (rows padded 257: bank-conflict-free).
// ---------------------------------------------------------------------------
__global__ __launch_bounds__(256) void interact_kernel(
    const float* __restrict__ neurons,
    const float* __restrict__ nqa, const float* __restrict__ nka,
    const float* __restrict__ nva,
    const int* __restrict__ topk_idx, const float* __restrict__ topk_w,
    float* __restrict__ agg)
{
    int t = blockIdx.x, tid = threadIdx.x;
    __shared__ float nq[KK][DD+1];
    __shared__ float nk[KK][DD+1];
    __shared__ float nv[KK][DD+1];
    __shared__ float ps[HH][KK][KK];
    __shared__ float tw[KK];
    __shared__ int sidx[KK];
    if (tid < KK) { tw[tid] = topk_w[t*KK+tid]; sidx[tid] = topk_idx[t*KK+tid]; }
    __syncthreads();
    for (int i = 0; i < KK; ++i) {
        int idx = sidx[i];
        nq[i][tid] = nqa[idx*DD+tid];
        nk[i][tid] = nka[idx*DD+tid];
        nv[i][tid] = nva[idx*DD+tid];
    }
    __syncthreads();
    #pragma unroll
    for (int r = 0; r < 4; ++r) {
        int lin = r*256 + tid;         // (h,i,j)
        int j = lin & 15, i = (lin >> 4) & 15, h = lin >> 8;
        const float* qp = &nq[i][h*DHH];
        const float* kp = &nk[j][h*DHH];
        float acc = 0.f;
        #pragma unroll 8
        for (int d = 0; d < DHH; ++d) acc = fmaf(qp[d], kp[d], acc);
        ps[h][i][j] = acc * 0.125f;
    }
    __syncthreads();
    if (tid < 64) {
        int h = tid >> 4, i = tid & 15;
        float mx = -3.4e38f;
        for (int j = 0; j < KK; ++j) mx = fmaxf(mx, ps[h][i][j]);
        float sum = 0.f;
        for (int j = 0; j < KK; ++j) { float e = expf(ps[h][i][j]-mx); ps[h][i][j] = e; sum += e; }
        float is = 1.0f/sum;
        for (int j = 0; j < KK; ++j) ps[h][i][j] *= is;
    }
    __syncthreads();
    int d = tid, h = d >> 6;
    float acc = 0.f;
    for (int i = 0; i < KK; ++i) {
        float g = 0.f;
        #pragma unroll
        for (int j = 0; j < KK; ++j) g = fmaf(ps[h][i][j], nv[j][d], g);
        acc += tw[i] * neurons[sidx[i]*DD + d] * g;
    }
    agg[t*DD+d] = acc;
}

// ---------------------------------------------------------------------------
// Pattern select: per-token scores, stable top-4, comb; bins (token,kp) by
// pattern for the grouped apply kernel.
// ---------------------------------------------------------------------------
__global__ __launch_bounds__(256) void pattern_select(
    const float* __restrict__ aggp, const float* __restrict__ ctxp,
    const float* __restrict__ n2p, const float* __restrict__ PQ,
    float* __restrict__ combined, float* __restrict__ tpwg,
    int* __restrict__ bin_count, int* __restrict__ bin_entry)
{
    int t = blockIdx.x, tid = threadIdx.x;
    __shared__ float mix[DD];
    __shared__ float ps[PP];
    __shared__ float psp[8][33];
    __shared__ int tpi[KPP];

    float a = aggp[t*DD+tid];
    float cx = ctxp[t*DD+tid];
    mix[tid] = 0.03125f * a + 0.5f * cx;   // 0.5/sqrt(256) = 0.03125
    combined[t*DD+tid] = n2p[t*DD+tid] + a;
    __syncthreads();

    {
        int p = tid & 31, g = tid >> 5;
        const float* pq = PQ + p*DD + g*32;
        const float* mp = mix + g*32;
        float acc = 0.f;
        #pragma unroll
        for (int d = 0; d < 32; ++d) acc = fmaf(mp[d], pq[d], acc);
        psp[g][p] = acc;
    }
    __syncthreads();
    if (tid < PP) {
        float s = 0.f;
        #pragma unroll
        for (int g = 0; g < 8; ++g) s += psp[g][tid];
        ps[tid] = s;
    }
    __syncthreads();

    if (tid == 0) {
        float vals[KPP];
        #pragma unroll
        for (int it = 0; it < KPP; ++it) {
            float bv = -3.4e38f; int bi = 0;
            for (int p = 0; p < PP; ++p) { float v = ps[p]; if (v > bv) { bv = v; bi = p; } }
            vals[it] = bv; tpi[it] = bi; ps[bi] = -3.4e38f;
        }
        float mx = vals[0];
        float e0 = expf(vals[0]-mx), e1 = expf(vals[1]-mx),
              e2 = expf(vals[2]-mx), e3 = expf(vals[3]-mx);
        float is = 1.0f/(e0+e1+e2+e3);
        tpwg[t*4+0]=e0*is; tpwg[t*4+1]=e1*is; tpwg[t*4+2]=e2*is; tpwg[t*4+3]=e3*is;
    }
    __syncthreads();
    if (tid < KPP) {
        int p = tpi[tid];
        int slot = atomicAdd(&bin_count[p], 1);
        bin_entry[p*TT + slot] = (t << 2) | tid;
    }
}

// ---------------------------------------------------------------------------
// Pattern apply: block = (chunk, pattern). Up to 16 tokens per chunk share one
// pattern's A and B (read once per chunk). Each (token,kp) contribution is
// written uniquely into hpat4[kp] slice; Wub epilogue sums the 4 slices.
// ---------------------------------------------------------------------------
__global__ __launch_bounds__(256) void pattern_apply(
    const float* __restrict__ comb, const float* __restrict__ tpwg,
    const int* __restrict__ bin_count, const int* __restrict__ bin_entry,
    const float* __restrict__ Aup, const float* __restrict__ Bup,
    float* __restrict__ hpat4)
{
    int p = blockIdx.y, cch = blockIdx.x;
    int cnt = bin_count[p];
    int base = cch * 16;
    if (base >= cnt) return;
    int nt = cnt - base; if (nt > 16) nt = 16;
    int tid = threadIdx.x;

    __shared__ int toks[16]; __shared__ int kps[16]; __shared__ float wts[16];
    __shared__ float combs[16][DD+1];   // padded: 4 i-groups hit distinct banks
    __shared__ float hmid[16][RR];      // row stride 256B: aligned float4

    if (tid < 16) {
        if (tid < nt) {
            int e = bin_entry[p*TT + base + tid];
            int t = e >> 2, kp = e & 3;
            toks[tid] = t; kps[tid] = kp; wts[tid] = tpwg[t*4 + kp];
        } else { toks[tid] = -1; wts[tid] = 0.f; }
    }
    __syncthreads();
    #pragma unroll
    for (int i = 0; i < 16; ++i) {
        int t = toks[i];
        combs[i][tid] = (t >= 0) ? comb[(size_t)t*DD + tid] : 0.f;
    }
    __syncthreads();

    // hmid[i][4g..4g+3] = wts[i] * (combs[i] . A[p][:, 4g..4g+3])
    {
        int i = tid >> 4, g = tid & 15;
        const float* Ap = Aup + (size_t)p*(DD*RR) + g*4;
        float a0=0.f, a1=0.f, a2=0.f, a3=0.f;
        #pragma unroll 8
        for (int d = 0; d < DD; ++d) {
            float cv = combs[i][d];
            float4 av = *(const float4*)&Ap[(size_t)d*RR];
            a0 = fmaf(cv, av.x, a0);
            a1 = fmaf(cv, av.y, a1);
            a2 = fmaf(cv, av.z, a2);
            a3 = fmaf(cv, av.w, a3);
        }
        float w = wts[i];
        hmid[i][g*4+0] = a0*w;
        hmid[i][g*4+1] = a1*w;
        hmid[i][g*4+2] = a2*w;
        hmid[i][g*4+3] = a3*w;
    }
    __syncthreads();

    // apply B[p]: thread owns ff cols 4*tid..4*tid+3; 16 token accumulators
    float4 acc[16];
    #pragma unroll
    for (int i = 0; i < 16; ++i) acc[i] = make_float4(0.f,0.f,0.f,0.f);
    const float* Bp = Bup + (size_t)p*(RR*FFD) + tid*4;
    for (int r4 = 0; r4 < RR/4; ++r4) {
        float4 b0 = *(const float4*)&Bp[(size_t)(r4*4+0)*FFD];
        float4 b1 = *(const float4*)&Bp[(size_t)(r4*4+1)*FFD];
        float4 b2 = *(const float4*)&Bp[(size_t)(r4*4+2)*FFD];
        float4 b3 = *(const float4*)&Bp[(size_t)(r4*4+3)*FFD];
        #pragma unroll
        for (int i = 0; i < 16; ++i) {
            float4 h = *(const float4*)&hmid[i][r4*4];
            acc[i].x = fmaf(h.x,b0.x, fmaf(h.y,b1.x, fmaf(h.z,b2.x, fmaf(h.w,b3.x, acc[i].x))));
            acc[i].y = fmaf(h.x,b0.y, fmaf(h.y,b1.y, fmaf(h.z,b2.y, fmaf(h.w,b3.y, acc[i].y))));
            acc[i].z = fmaf(h.x,b0.z, fmaf(h.y,b1.z, fmaf(h.z,b2.z, fmaf(h.w,b3.z, acc[i].z))));
            acc[i].w = fmaf(h.x,b0.w, fmaf(h.y,b1.w, fmaf(h.z,b2.w, fmaf(h.w,b3.w, acc[i].w))));
        }
    }
    #pragma unroll
    for (int i = 0; i < 16; ++i) {
        int t = toks[i];
        if (t >= 0)
            *(float4*)&hpat4[(size_t)kps[i]*(TT*FFD) + (size_t)t*FFD + tid*4] = acc[i];
    }
}

// ---------------------------------------------------------------------------
extern "C" void kernel_launch(void* const* d_in, const int* in_sizes, int n_in,
                              void* d_out, int out_size, void* d_ws, size_t ws_size,
                              hipStream_t stream)
{
    const float* x        = (const float*)d_in[0];
    const float* g1       = (const float*)d_in[1];
    const float* b1       = (const float*)d_in[2];
    const float* g2       = (const float*)d_in[3];
    const float* b2       = (const float*)d_in[4];
    const float* Wq       = (const float*)d_in[5];
    const float* bq       = (const float*)d_in[6];
    const float* Wk       = (const float*)d_in[7];
    const float* bk       = (const float*)d_in[8];
    const float* Wv       = (const float*)d_in[9];
    const float* bv       = (const float*)d_in[10];
    const float* Wpath    = (const float*)d_in[11];
    const float* bpath    = (const float*)d_in[12];
    const float* neurons  = (const float*)d_in[13];
    const float* Wnq      = (const float*)d_in[14];
    const float* bnq      = (const float*)d_in[15];
    const float* Wnk      = (const float*)d_in[16];
    const float* bnk      = (const float*)d_in[17];
    const float* Wnv      = (const float*)d_in[18];
    const float* bnv      = (const float*)d_in[19];
    const float* PQ       = (const float*)d_in[20];
    const float* Aup      = (const float*)d_in[21];
    const float* Bup      = (const float*)d_in[22];
    const float* Wub      = (const float*)d_in[23];
    const float* bub      = (const float*)d_in[24];
    const float* Wd       = (const float*)d_in[25];
    const float* bd       = (const float*)d_in[26];

    float* out0    = (float*)d_out;              // [B,S,D] residual output
    float* out_idx = out0 + (size_t)TT*DD;       // [B,S,K] indices (as float)

    // workspace carve-up (floats)
    float* ws = (float*)d_ws;
    float* n1    = ws; ws += TT*DD;
    float* n2    = ws; ws += TT*DD;
    float* qb    = ws; ws += TT*DD;
    float* kb    = ws; ws += TT*DD;
    float* vb    = ws; ws += TT*DD;
    float* ctx   = ws; ws += TT*DD;
    float* ts    = ws; ws += TT*NN;
    float* cs    = ws; ws += TT*NN;
    float* nqa   = ws; ws += NN*DD;
    float* nka   = ws; ws += NN*DD;
    float* nva   = ws; ws += NN*DD;
    float* agg   = ws; ws += TT*DD;
    float* comb  = ws; ws += TT*DD;
    float* hpat4 = ws; ws += 4*TT*FFD;           // 4 slices (one per kp)
    float* hb    = ws; ws += TT*FFD;
    float* part  = ws; ws += 4*TT*DD;            // split-K partials for Wd
    float* tkw   = ws; ws += TT*KK;
    float* tpwg  = ws; ws += TT*KPP;
    int*   tki   = (int*)ws; ws += TT*KK;
    int*   binc  = (int*)ws; ws += 32;
    int*   bine  = (int*)ws; ws += 32*TT;

    dim3 blk(256);

    // 0. zero bin counters (ws is re-poisoned before every call)
    zero_kernel<<<1, 64, 0, stream>>>(binc, 32);

    // 1. LayerNorms
    ln_kernel<<<TT, blk, 0, stream>>>(x, g1, b1, g2, b2, n1, n2);

    // 2. QKV projections batched (M=1024,N=256,K=256, z=3)
    {
        GemmSet sq{n1, Wq, bq, qb, 0}, sk{n1, Wk, bk, kb, 0}, sv{n1, Wv, bv, vb, 0};
        gemm3_kernel<<<dim3(DD/64, TT/64, 3), blk, 0, stream>>>(sq, sk, sv, TT, DD, DD, 0);
    }

    // 3. Neuron projections batched (M=512,N=256,K=256, z=3); nv -> sigmoid
    {
        GemmSet s0{neurons, Wnq, bnq, nqa, 0}, s1{neurons, Wnk, bnk, nka, 0},
                s2{neurons, Wnv, bnv, nva, 1};
        gemm3_kernel<<<dim3(DD/64, NN/64, 3), blk, 0, stream>>>(s0, s1, s2, NN, DD, DD, 0);
    }

    // 4. Attention -> context  (flash-style, 256 blocks)
    attn_kernel<<<BB*HH*(SS/QT), blk, 0, stream>>>(qb, kb, vb, ctx);

    // 5. token/context scores vs neurons^T (M=1024,N=512,K=256, transB, z=2)
    {
        GemmSet s0{n1, neurons, nullptr, ts, 0}, s1{ctx, neurons, nullptr, cs, 0};
        gemm3_kernel<<<dim3(NN/64, TT/64, 2), blk, 0, stream>>>(s0, s1, s1, TT, NN, DD, 1);
    }

    // 6. path weights + mix + top-16
    route_kernel<<<TT, blk, 0, stream>>>(n1, ctx, Wpath, bpath, ts, cs, tki, tkw, out_idx);

    // 7. interaction FFN -> aggregated
    interact_kernel<<<TT, blk, 0, stream>>>(neurons, nqa, nka, nva, tki, tkw, agg);

    // 8a. pattern select -> comb, tpw, bins
    pattern_select<<<TT, blk, 0, stream>>>(agg, ctx, n2, PQ, comb, tpwg, binc, bine);

    // 8b. pattern apply (grouped by pattern) -> hpat4 slices
    pattern_apply<<<dim3(TT/16, PP), blk, 0, stream>>>(comb, tpwg, binc, bine, Aup, Bup, hpat4);

    // 9. h = gelu(0.1*(comb@Wub+bub) + 0.9*sum(hpat4))   (M=1024,N=1024,K=256)
    gemm_kernel<<<dim3(FFD/64, TT/64), blk, 0, stream>>>(comb, Wub, bub, hpat4, hb, TT, FFD, DD, 0, 2);

    // 10. out = x + h@Wd + bd  via split-K(4) + combine  (M=1024,N=256,K=1024)
    gemm_splitk_kernel<<<dim3(DD/64, TT/64, 4), blk, 0, stream>>>(hb, Wd, part, TT, DD, FFD, FFD/4);
    combine_wd_kernel<<<TT*DD/256, blk, 0, stream>>>(part, x, bd, out0);
}